// Round 6
// baseline (2096.285 us; speedup 1.0000x reference)
//
#include <hip/hip_runtime.h>

#define N_NODES 100000
#define NPAD    100096      // 3128 * 32
#define NTILES  3128        // 32-row dst tiles
#define NKEYS   (NTILES * 5)
#define G_GRAPHS 256
#define IN_F 162
#define KPAD0 192
#define HID 128
#define R_REL 5
#define L_LAYERS 2
#define M5 (R_REL * N_NODES)

typedef __attribute__((ext_vector_type(8))) short bf16x8;
typedef __attribute__((ext_vector_type(4))) float f32x4;

__device__ __forceinline__ short f2bf(float f) {
    union { float f; unsigned u; } v; v.f = f;
    unsigned r = (v.u + 0x7fffu + ((v.u >> 16) & 1u)) >> 16;
    return (short)r;
}
__device__ __forceinline__ float bf2f(unsigned short u) {
    union { unsigned u; float f; } v; v.u = ((unsigned)u) << 16;
    return v.f;
}

// ---------------- CSR build: per-(dst,rel) counts (for invc) + per-(tile,rel) key counts ----------------
__global__ void k_count(const int* e0, const int* e1, const int* e2,
                        const int* e3, const int* e4, int* cnt, int* kcnt, int E) {
    int gid = blockIdx.x * 256 + threadIdx.x;
    if (gid >= R_REL * E) return;
    int r = gid / E, e = gid - r * E;
    const int* ei = (r == 0) ? e0 : (r == 1) ? e1 : (r == 2) ? e2 : (r == 3) ? e3 : e4;
    int dst = ei[E + e];
    atomicAdd(&cnt[r * N_NODES + dst], 1);
    atomicAdd(&kcnt[(dst >> 5) * 5 + r], 1);
}

__global__ void k_invc(const int* __restrict__ cnt, float* __restrict__ invc, int n) {
    int i = blockIdx.x * 256 + threadIdx.x;
    if (i < n) invc[i] = 1.0f / (float)max(cnt[i], 1);
}

// single-block exclusive scan of kcnt -> kstart (+ kcur copy)
__global__ __launch_bounds__(256)
void k_scan_keys(const int* __restrict__ kcnt, int* __restrict__ kstart,
                 int* __restrict__ kcur) {
    __shared__ int ts[256];
    int t = threadIdx.x;
    const int per = (NKEYS + 255) / 256;   // 62
    int base = t * per;
    int sum = 0;
    for (int j = 0; j < per; j++) if (base + j < NKEYS) sum += kcnt[base + j];
    ts[t] = sum; __syncthreads();
    for (int o = 1; o < 256; o <<= 1) {
        int x = (t >= o) ? ts[t - o] : 0;
        __syncthreads();
        ts[t] += x;
        __syncthreads();
    }
    int run = ts[t] - sum;
    for (int j = 0; j < per; j++) {
        if (base + j < NKEYS) { kstart[base + j] = run; kcur[base + j] = run; run += kcnt[base + j]; }
    }
    if (t == 255) kstart[NKEYS] = ts[255];
}

// record = (src << 5) | dloc ; mw = 1/deg(dst, rel)
__global__ void k_fillk(const int* e0, const int* e1, const int* e2,
                        const int* e3, const int* e4, int* kcur,
                        const float* __restrict__ invc,
                        int* __restrict__ mrec, float* __restrict__ mw, int E) {
    int gid = blockIdx.x * 256 + threadIdx.x;
    if (gid >= R_REL * E) return;
    int r = gid / E, e = gid - r * E;
    const int* ei = (r == 0) ? e0 : (r == 1) ? e1 : (r == 2) ? e2 : (r == 3) ? e3 : e4;
    int src = ei[e], dst = ei[E + e];
    int pos = atomicAdd(&kcur[(dst >> 5) * 5 + r], 1);
    mrec[pos] = (src << 5) | (dst & 31);
    mw[pos] = invc[r * N_NODES + dst];
}

// ---------------- X fp32 -> bf16, padded [NPAD][192] (zeros in pad) ----------------
__global__ void k_castX(const float* __restrict__ X, unsigned short* __restrict__ Xb) {
    int gid = blockIdx.x * 256 + threadIdx.x;
    if (gid >= NPAD * KPAD0) return;
    int row = gid / KPAD0, k = gid - row * KPAD0;
    float v = (row < N_NODES && k < IN_F) ? X[(size_t)row * IN_F + k] : 0.f;
    Xb[gid] = (unsigned short)f2bf(v);
}

// ---------------- weight pre-transpose (fp32 -> bf16, [seg][col][Kpad]) ----------------
__global__ void k_tw0(const float* __restrict__ root0, const float* __restrict__ W0,
                      short* __restrict__ out) {
    int gid = blockIdx.x * 256 + threadIdx.x;   // 6*128*192
    if (gid >= 6 * 128 * KPAD0) return;
    int chunk = gid / (128 * KPAD0);
    int rem = gid - chunk * 128 * KPAD0;
    int col = rem / KPAD0;
    int k = rem - col * KPAD0;
    float v = 0.f;
    if (k < IN_F)
        v = (chunk == 0) ? root0[k * HID + col]
                         : W0[((size_t)(chunk - 1) * IN_F + k) * HID + col];
    out[gid] = f2bf(v);
}

__global__ void k_twl(const float* __restrict__ rootl, const float* __restrict__ Wl,
                      short* __restrict__ out) {
    int gid = blockIdx.x * 256 + threadIdx.x;   // 2*6*128*128
    if (gid >= L_LAYERS * 6 * 128 * HID) return;
    int l = gid / (6 * 128 * HID);
    int rem = gid - l * 6 * 128 * HID;
    int chunk = rem / (128 * HID);
    int rem2 = rem - chunk * 128 * HID;
    int col = rem2 / HID;
    int k = rem2 - col * HID;
    float v = (chunk == 0) ? rootl[((size_t)l * HID + k) * HID + col]
                           : Wl[(((size_t)l * R_REL + (chunk - 1)) * HID + k) * HID + col];
    out[gid] = f2bf(v);
}

// ---------------- fused layer: gather-into-LDS + MFMA, no xagg intermediate ----------------
// H = relu(bias + sum_{seg=0..5} A_seg @ W_seg^T); A_0 = Xin rows, A_r = per-rel mean of
// gathered Xin[src] rows. Block = 32 dst rows, 4 waves in 2x2 (16 rows x 64 cols each).
template<int SEG>
__global__ __launch_bounds__(256)
void layer_fused(const unsigned short* __restrict__ Xin,   // [NPAD][SEG]
                 const short* __restrict__ Wt,             // [6][128][SEG]
                 const int* __restrict__ kstart,           // [NKEYS+1]
                 const int* __restrict__ mrec,             // (src<<5)|dloc
                 const float* __restrict__ mw,
                 const float* __restrict__ bias,
                 unsigned short* __restrict__ H) {         // [NPAD][128]
    constexpr int SAP = SEG + 4;      // fp32 LDS row stride (132 / 196: stride%32==4 -> 2-way)
    constexpr int SBP = SEG + 8;      // bf16 LDS row stride (136 / 200 shorts)
    constexpr int C8 = SEG / 8;
    __shared__ float Asf[32 * SAP];
    __shared__ short Bsh[128 * SBP];

    const int tid = threadIdx.x;
    const int tile = blockIdx.x;
    const int row0 = tile * 32;
    const int lane = tid & 63, wv = tid >> 6;
    const int quad = lane >> 4, l16 = lane & 15;
    const int wr0 = (wv >> 1) * 16, wc0 = (wv & 1) * 64;

    float bv[4];
    #pragma unroll
    for (int j = 0; j < 4; j++) bv[j] = bias[wc0 + j * 16 + l16];

    f32x4 acc[4];
    #pragma unroll
    for (int j = 0; j < 4; j++) acc[j] = (f32x4){0.f, 0.f, 0.f, 0.f};

    for (int seg = 0; seg < 6; seg++) {
        __syncthreads();   // prev K-loop readers done
        // ---- fill Asf ----
        if (seg == 0) {
            for (int c = tid; c < 32 * C8; c += 256) {
                int r = c / C8, c8 = (c - r * C8) * 8;
                bf16x8 v = *(const bf16x8*)&Xin[(size_t)(row0 + r) * SEG + c8];
                float* dp = &Asf[r * SAP + c8];
                #pragma unroll
                for (int j = 0; j < 8; j++) dp[j] = bf2f((unsigned short)v[j]);
            }
        } else {
            for (int c = tid; c < 32 * (SEG / 4); c += 256) {
                int r = c / (SEG / 4), c4 = (c - r * (SEG / 4)) * 4;
                *(f32x4*)&Asf[r * SAP + c4] = (f32x4){0.f, 0.f, 0.f, 0.f};
            }
        }
        // ---- stage Bsh (W for this segment; L2-hot) ----
        const short* Wc = Wt + (size_t)seg * 128 * SEG;
        for (int c = tid; c < 128 * C8; c += 256) {
            int r = c / C8, c8 = (c - r * C8) * 8;
            *(bf16x8*)&Bsh[r * SBP + c8] = *(const bf16x8*)&Wc[r * SEG + c8];
        }
        __syncthreads();
        // ---- gather edges for this (tile, relation) ----
        if (seg >= 1) {
            int key = tile * 5 + (seg - 1);
            int ks = kstart[key], ke = kstart[key + 1];
            int idx = ks + wv;
            if (idx < ke) {
                int rec = mrec[idx];
                float w = mw[idx];
                unsigned u = *(const unsigned*)&Xin[(size_t)(rec >> 5) * SEG + 2 * lane];
                unsigned short t3 = (SEG == KPAD0) ? Xin[(size_t)(rec >> 5) * SEG + 128 + lane] : (unsigned short)0;
                while (true) {
                    int nidx = idx + 4;
                    int nrec = 0; float nw = 0.f; unsigned nu = 0; unsigned short nt3 = 0;
                    if (nidx < ke) {   // prefetch next record's row (overlaps LDS atomics)
                        nrec = mrec[nidx];
                        nw = mw[nidx];
                        nu = *(const unsigned*)&Xin[(size_t)(nrec >> 5) * SEG + 2 * lane];
                        if (SEG == KPAD0) nt3 = Xin[(size_t)(nrec >> 5) * SEG + 128 + lane];
                    }
                    int dloc = rec & 31;
                    float v0 = bf2f((unsigned short)(u & 0xffff)) * w;
                    float v1 = bf2f((unsigned short)(u >> 16)) * w;
                    atomicAdd(&Asf[dloc * SAP + 2 * lane], v0);
                    atomicAdd(&Asf[dloc * SAP + 2 * lane + 1], v1);
                    if (SEG == KPAD0) atomicAdd(&Asf[dloc * SAP + 128 + lane], bf2f(t3) * w);
                    if (nidx >= ke) break;
                    idx = nidx; rec = nrec; w = nw; u = nu; t3 = nt3;
                }
            }
            __syncthreads();
        }
        // ---- MFMA K-loop over this segment ----
        #pragma unroll
        for (int kb = 0; kb < SEG / 32; kb++) {
            const float* ap = &Asf[(wr0 + l16) * SAP + kb * 32 + quad * 8];
            f32x4 a0 = *(const f32x4*)ap;
            f32x4 a1 = *(const f32x4*)(ap + 4);
            bf16x8 af;
            #pragma unroll
            for (int j = 0; j < 4; j++) { af[j] = f2bf(a0[j]); af[4 + j] = f2bf(a1[j]); }
            #pragma unroll
            for (int j = 0; j < 4; j++) {
                bf16x8 bf8 = *(const bf16x8*)&Bsh[(wc0 + j * 16 + l16) * SBP + kb * 32 + quad * 8];
                acc[j] = __builtin_amdgcn_mfma_f32_16x16x32_bf16(af, bf8, acc[j], 0, 0, 0);
            }
        }
    }
    __syncthreads();
    // ---- epilogue: bias + relu -> Bsh (bf16) -> coalesced stores ----
    #pragma unroll
    for (int j = 0; j < 4; j++)
        #pragma unroll
        for (int reg = 0; reg < 4; reg++) {
            float v = fmaxf(acc[j][reg] + bv[j], 0.f);
            Bsh[(wr0 + quad * 4 + reg) * SBP + wc0 + j * 16 + l16] = f2bf(v);
        }
    __syncthreads();
    for (int c = tid; c < 32 * 16; c += 256) {
        int r = c >> 4, c8 = (c & 15) * 8;
        bf16x8 v = *(const bf16x8*)&Bsh[r * SBP + c8];
        *(bf16x8*)&H[(size_t)(row0 + r) * HID + c8] = v;
    }
}

// ---------------- readout ----------------
__global__ __launch_bounds__(128)
void k_pool(const unsigned short* __restrict__ h, const int* __restrict__ batch,
            float* __restrict__ pooled) {
    int c = threadIdx.x;
    int start = blockIdx.x * 128;
    if (start >= N_NODES) return;
    int end = min(start + 128, N_NODES);
    int g = batch[start];
    float s = 0.f;
    for (int i = start; i < end; i++) {
        int gi = batch[i];
        if (gi != g) { atomicAdd(&pooled[g * HID + c], s); s = 0.f; g = gi; }
        s += bf2f(h[(size_t)i * HID + c]);
    }
    atomicAdd(&pooled[g * HID + c], s);
}

__device__ int lower_bound_i(const int* a, int n, int v) {
    int lo = 0, hi = n;
    while (lo < hi) {
        int mid = (lo + hi) >> 1;
        if (a[mid] < v) lo = mid + 1; else hi = mid;
    }
    return lo;
}

__global__ __launch_bounds__(128)
void k_mlp(const float* __restrict__ pooled, const int* __restrict__ batch,
           const float* __restrict__ Wc1, const float* __restrict__ bc1,
           const float* __restrict__ Wc2, const float* __restrict__ bc2,
           const float* __restrict__ Wc3, const float* __restrict__ bc3,
           float* __restrict__ out) {
    int g = blockIdx.x;
    int c = threadIdx.x;
    __shared__ int range[2];
    if (c == 0) range[0] = lower_bound_i(batch, N_NODES, g);
    if (c == 1) range[1] = lower_bound_i(batch, N_NODES, g + 1);
    __syncthreads();
    float denom = fmaxf((float)(range[1] - range[0]), 1.0f);
    __shared__ float row[HID], h1[HID], h2[HID];
    row[c] = pooled[g * HID + c] / denom;
    __syncthreads();
    float acc = bc1[c];
    for (int k = 0; k < HID; k++) acc += row[k] * Wc1[k * HID + c];
    h1[c] = fmaxf(acc, 0.f);
    __syncthreads();
    acc = bc2[c];
    for (int k = 0; k < HID; k++) acc += h1[k] * Wc2[k * HID + c];
    h2[c] = fmaxf(acc, 0.f);
    __syncthreads();
    float t = h2[c] * Wc3[c];
    for (int off = 32; off > 0; off >>= 1) t += __shfl_down(t, off, 64);
    __shared__ float part[2];
    if ((c & 63) == 0) part[c >> 6] = t;
    __syncthreads();
    if (c == 0) out[g] = part[0] + part[1] + bc3[0];
}

// ---------------- launcher ----------------
extern "C" void kernel_launch(void* const* d_in, const int* in_sizes, int n_in,
                              void* d_out, int out_size, void* d_ws, size_t ws_size,
                              hipStream_t stream) {
    const float* X     = (const float*)d_in[0];
    const int*   batch = (const int*)d_in[1];
    const int*   e0 = (const int*)d_in[2];
    const int*   e1 = (const int*)d_in[3];
    const int*   e2 = (const int*)d_in[4];
    const int*   e3 = (const int*)d_in[5];
    const int*   e4 = (const int*)d_in[6];
    const float* W0    = (const float*)d_in[7];
    const float* root0 = (const float*)d_in[8];
    const float* b0    = (const float*)d_in[9];
    const float* Wl    = (const float*)d_in[10];
    const float* rootl = (const float*)d_in[11];
    const float* bl    = (const float*)d_in[12];
    const float* Wc1   = (const float*)d_in[13];
    const float* bc1   = (const float*)d_in[14];
    const float* Wc2   = (const float*)d_in[15];
    const float* bc2   = (const float*)d_in[16];
    const float* Wc3   = (const float*)d_in[17];
    const float* bc3   = (const float*)d_in[18];
    const int E = in_sizes[2] / 2;
    const int NE = R_REL * E;

    char* base = (char*)d_ws;
    size_t o = 0;
    auto carve = [&](size_t bytes) -> char* {
        char* p = base + o;
        o = (o + bytes + 255) & ~(size_t)255;
        return p;
    };
    unsigned short* Xb   = (unsigned short*)carve((size_t)NPAD * KPAD0 * 2);
    unsigned short* hA   = (unsigned short*)carve((size_t)NPAD * HID * 2);
    unsigned short* hB   = (unsigned short*)carve((size_t)NPAD * HID * 2);
    int*   cnt    = (int*)carve((size_t)M5 * 4);
    float* invc   = (float*)carve((size_t)M5 * 4);
    int*   kcnt   = (int*)carve((size_t)NKEYS * 4);
    int*   kstart = (int*)carve((size_t)(NKEYS + 1) * 4);
    int*   kcur   = (int*)carve((size_t)NKEYS * 4);
    int*   mrec   = (int*)carve((size_t)NE * 4);
    float* mw     = (float*)carve((size_t)NE * 4);
    float* pooled = (float*)carve((size_t)G_GRAPHS * HID * 4);
    short* Wt0    = (short*)carve((size_t)6 * 128 * KPAD0 * 2);
    short* Wtl    = (short*)carve((size_t)L_LAYERS * 6 * 128 * HID * 2);

    // ---- CSR build + casts ----
    hipMemsetAsync(cnt, 0, (size_t)M5 * 4, stream);
    hipMemsetAsync(kcnt, 0, (size_t)NKEYS * 4, stream);
    hipMemsetAsync(pooled, 0, (size_t)G_GRAPHS * HID * 4, stream);
    int eg = (NE + 255) / 256;
    k_count<<<eg, 256, 0, stream>>>(e0, e1, e2, e3, e4, cnt, kcnt, E);
    k_invc<<<(M5 + 255) / 256, 256, 0, stream>>>(cnt, invc, M5);
    k_scan_keys<<<1, 256, 0, stream>>>(kcnt, kstart, kcur);
    k_fillk<<<eg, 256, 0, stream>>>(e0, e1, e2, e3, e4, kcur, invc, mrec, mw, E);
    k_castX<<<(NPAD * KPAD0 + 255) / 256, 256, 0, stream>>>(X, Xb);
    k_tw0<<<(6 * 128 * KPAD0 + 255) / 256, 256, 0, stream>>>(root0, W0, Wt0);
    k_twl<<<(L_LAYERS * 6 * 128 * HID + 255) / 256, 256, 0, stream>>>(rootl, Wl, Wtl);

    // ---- layers (fully fused: gather + GEMM + bias + relu) ----
    layer_fused<KPAD0><<<NTILES, 256, 0, stream>>>(Xb, Wt0, kstart, mrec, mw, b0, hA);
    layer_fused<HID><<<NTILES, 256, 0, stream>>>(hA, Wtl, kstart, mrec, mw, bl, hB);
    layer_fused<HID><<<NTILES, 256, 0, stream>>>(hB, Wtl + (size_t)6 * 128 * HID,
                                                 kstart, mrec, mw, bl + HID, hA);

    // ---- readout ----
    k_pool<<<(N_NODES + 127) / 128, 128, 0, stream>>>(hA, batch, pooled);
    k_mlp<<<G_GRAPHS, 128, 0, stream>>>(pooled, batch, Wc1, bc1, Wc2, bc2, Wc3, bc3, (float*)d_out);
}

// Round 7
// 738.657 us; speedup vs baseline: 2.8380x; 2.8380x over previous
//
#include <hip/hip_runtime.h>

#define N_NODES 100000
#define NPAD    100096      // 782 * 128
#define NTILES  782
#define G_GRAPHS 256
#define IN_F 162
#define KPAD0 192
#define HID 128
#define R_REL 5
#define L_LAYERS 2
#define M5 (R_REL * N_NODES)

typedef __attribute__((ext_vector_type(8))) short bf16x8;
typedef __attribute__((ext_vector_type(4))) float f32x4;

__device__ __forceinline__ short f2bf(float f) {
    union { float f; unsigned u; } v; v.f = f;
    unsigned r = (v.u + 0x7fffu + ((v.u >> 16) & 1u)) >> 16;
    return (short)r;
}
__device__ __forceinline__ float bf2f(unsigned short u) {
    union { unsigned u; float f; } v; v.u = ((unsigned)u) << 16;
    return v.f;
}

// ---------------- CSR build (merged across relations, dst-major) ----------------
__global__ void k_count(const int* e0, const int* e1, const int* e2,
                        const int* e3, const int* e4, int* cnt, int E) {
    int gid = blockIdx.x * 256 + threadIdx.x;
    if (gid >= R_REL * E) return;
    int r = gid / E, e = gid - r * E;
    const int* ei = (r == 0) ? e0 : (r == 1) ? e1 : (r == 2) ? e2 : (r == 3) ? e3 : e4;
    atomicAdd(&cnt[r * N_NODES + ei[E + e]], 1);
}

__global__ __launch_bounds__(256) void k_scan1(const int* __restrict__ cnt,
                                               int* __restrict__ off, int* __restrict__ bsum) {
    __shared__ int ts[256];
    int t = threadIdx.x;
    int base = blockIdx.x * 1024 + t * 4;
    int v[4];
    #pragma unroll
    for (int j = 0; j < 4; j++) {
        int d = base + j;
        int s = 0;
        if (d < N_NODES) {
            #pragma unroll
            for (int r = 0; r < R_REL; r++) s += cnt[r * N_NODES + d];
        }
        v[j] = s;
    }
    int tsum = v[0] + v[1] + v[2] + v[3];
    ts[t] = tsum; __syncthreads();
    for (int o = 1; o < 256; o <<= 1) {
        int x = (t >= o) ? ts[t - o] : 0;
        __syncthreads();
        ts[t] += x;
        __syncthreads();
    }
    if (t == 255) bsum[blockIdx.x] = ts[255];
    int run = ts[t] - tsum;
    #pragma unroll
    for (int j = 0; j < 4; j++) { if (base + j < N_NODES) off[base + j] = run; run += v[j]; }
}

__global__ __launch_bounds__(512) void k_scan2(int* bsum, int nblk) {
    __shared__ int ts[512];
    int t = threadIdx.x;
    int v = (t < nblk) ? bsum[t] : 0;
    ts[t] = v; __syncthreads();
    for (int o = 1; o < 512; o <<= 1) {
        int x = (t >= o) ? ts[t - o] : 0;
        __syncthreads();
        ts[t] += x;
        __syncthreads();
    }
    if (t < nblk) bsum[t] = ts[t] - v;   // exclusive
}

__global__ void k_scan3(const int* __restrict__ off, const int* __restrict__ bsum,
                        int* __restrict__ mstart, int* __restrict__ mcur,
                        const int* __restrict__ cnt, float* __restrict__ invc) {
    int i = blockIdx.x * 256 + threadIdx.x;
    if (i >= N_NODES) return;
    int o = off[i] + bsum[i >> 10];
    mstart[i] = o;
    mcur[i] = o;
    int tc = 0;
    #pragma unroll
    for (int r = 0; r < R_REL; r++) {
        int c = cnt[r * N_NODES + i];
        tc += c;
        invc[r * N_NODES + i] = 1.0f / (float)max(c, 1);
    }
    if (i == N_NODES - 1) mstart[N_NODES] = o + tc;
}

// mrec = absolute ushort-offset of source row in Y; mw = 1/deg(dst, r)
__global__ void k_fill(const int* e0, const int* e1, const int* e2,
                       const int* e3, const int* e4, int* mcur,
                       const float* __restrict__ invc,
                       int* __restrict__ mrec, float* __restrict__ mw, int E) {
    int gid = blockIdx.x * 256 + threadIdx.x;
    if (gid >= R_REL * E) return;
    int r = gid / E, e = gid - r * E;
    const int* ei = (r == 0) ? e0 : (r == 1) ? e1 : (r == 2) ? e2 : (r == 3) ? e3 : e4;
    int src = ei[e], dst = ei[E + e];
    int pos = atomicAdd(&mcur[dst], 1);
    mrec[pos] = ((1 + r) * NPAD + src) * HID;
    mw[pos] = invc[r * N_NODES + dst];
}

// ---------------- weight pre-transpose (fp32 -> bf16, [chunk][col][Kpad]) ----------------
__global__ void k_tw0(const float* __restrict__ root0, const float* __restrict__ W0,
                      short* __restrict__ out) {
    int gid = blockIdx.x * 256 + threadIdx.x;   // 6*128*192
    if (gid >= 6 * 128 * KPAD0) return;
    int chunk = gid / (128 * KPAD0);
    int rem = gid - chunk * 128 * KPAD0;
    int col = rem / KPAD0;
    int k = rem - col * KPAD0;
    float v = 0.f;
    if (k < IN_F)
        v = (chunk == 0) ? root0[k * HID + col]
                         : W0[((size_t)(chunk - 1) * IN_F + k) * HID + col];
    out[gid] = f2bf(v);
}

__global__ void k_twl(const float* __restrict__ rootl, const float* __restrict__ Wl,
                      short* __restrict__ out) {
    int gid = blockIdx.x * 256 + threadIdx.x;   // 2*6*128*128
    if (gid >= L_LAYERS * 6 * 128 * HID) return;
    int l = gid / (6 * 128 * HID);
    int rem = gid - l * 6 * 128 * HID;
    int chunk = rem / (128 * HID);
    int rem2 = rem - chunk * 128 * HID;
    int col = rem2 / HID;
    int k = rem2 - col * HID;
    float v = (chunk == 0) ? rootl[((size_t)l * HID + k) * HID + col]
                           : Wl[(((size_t)l * R_REL + (chunk - 1)) * HID + k) * HID + col];
    out[gid] = f2bf(v);
}

// ---------------- MFMA GEMM: A fragments held in registers across all 6 chunks ----------------
// One block = one 128-row tile; loops 6 weight chunks; A read from global exactly once.
// B staged per chunk in one LDS buffer, reused for the coalesced-store epilogue.
template<int SEG, bool A_F32, int MINW>
__global__ __launch_bounds__(256, MINW)
void gemm_reg(const void* __restrict__ Av, const short* __restrict__ Wt,
              unsigned short* __restrict__ Y) {
    constexpr int KSEG = SEG / 32;
    constexpr int SBP = SEG + 8;
    __shared__ short Bs[128 * SBP];
    const int tid = threadIdx.x;
    const int row0 = blockIdx.x * 128;
    const int lane = tid & 63, wv = tid >> 6;
    const int quad = lane >> 4, l16 = lane & 15;
    const int wr0 = (wv >> 1) * 64, wc0 = (wv & 1) * 64;

    // ---- load ALL A fragments into registers (once per block) ----
    bf16x8 af[KSEG][4];
    #pragma unroll
    for (int i = 0; i < 4; i++) {
        int grow = row0 + wr0 + i * 16 + l16;
        if (A_F32) {
            const float* rp = (const float*)Av + (size_t)grow * IN_F;
            bool ok = grow < N_NODES;
            #pragma unroll
            for (int kb = 0; kb < KSEG; kb++) {
                bf16x8 v;
                if (kb < 5) {            // k+8 <= 160+... <= 162 for kb<=4: full vectors
                    int k = kb * 32 + quad * 8;
                    #pragma unroll
                    for (int h = 0; h < 4; h++) {
                        float2 f2 = ok ? *(const float2*)(rp + k + 2 * h)
                                       : make_float2(0.f, 0.f);
                        v[2 * h] = f2bf(f2.x); v[2 * h + 1] = f2bf(f2.y);
                    }
                } else {                 // kb==5: k in [160,191], only 160,161 valid
                    int k = 160 + quad * 8;
                    #pragma unroll
                    for (int j = 0; j < 8; j++) {
                        int kk = k + j;
                        float f = (ok && kk < IN_F) ? rp[kk] : 0.f;
                        v[j] = f2bf(f);
                    }
                }
                af[kb][i] = v;
            }
        } else {
            const unsigned short* Ab = (const unsigned short*)Av;
            #pragma unroll
            for (int kb = 0; kb < KSEG; kb++)
                af[kb][i] = *(const bf16x8*)&Ab[(size_t)grow * SEG + kb * 32 + quad * 8];
        }
    }

    for (int chunk = 0; chunk < 6; chunk++) {
        if (chunk) __syncthreads();      // prev epilogue's Bs readers done
        const short* Wc = Wt + (size_t)chunk * 128 * SEG;
        for (int c = tid; c < 128 * (SEG / 8); c += 256) {
            int r = c / (SEG / 8), c8 = (c - r * (SEG / 8)) * 8;
            *(bf16x8*)&Bs[r * SBP + c8] = *(const bf16x8*)&Wc[r * SEG + c8];
        }
        __syncthreads();

        f32x4 acc[4][4];
        #pragma unroll
        for (int i = 0; i < 4; i++)
            #pragma unroll
            for (int j = 0; j < 4; j++) acc[i][j] = (f32x4){0.f, 0.f, 0.f, 0.f};

        #pragma unroll
        for (int kb = 0; kb < KSEG; kb++) {
            bf16x8 bfr[4];
            #pragma unroll
            for (int j = 0; j < 4; j++)
                bfr[j] = *(const bf16x8*)&Bs[(wc0 + j * 16 + l16) * SBP + kb * 32 + quad * 8];
            #pragma unroll
            for (int i = 0; i < 4; i++)
                #pragma unroll
                for (int j = 0; j < 4; j++)
                    acc[i][j] = __builtin_amdgcn_mfma_f32_16x16x32_bf16(af[kb][i], bfr[j], acc[i][j], 0, 0, 0);
        }
        __syncthreads();   // waves done reading Bs

        // epilogue: acc -> Bs (bf16), then full-line coalesced stores
        #pragma unroll
        for (int i = 0; i < 4; i++)
            #pragma unroll
            for (int j = 0; j < 4; j++)
                #pragma unroll
                for (int reg = 0; reg < 4; reg++)
                    Bs[(wr0 + i * 16 + quad * 4 + reg) * SBP + wc0 + j * 16 + l16] =
                        f2bf(acc[i][j][reg]);
        __syncthreads();

        unsigned short* Yc = Y + (size_t)chunk * NPAD * HID + (size_t)row0 * HID;
        #pragma unroll
        for (int s = 0; s < 8; s++) {
            int row = (tid >> 4) + s * 16;
            int col = (tid & 15) * 8;
            bf16x8 v = *(const bf16x8*)&Bs[row * SBP + col];
            *(bf16x8*)&Yc[(size_t)row * HID + col] = v;
        }
    }
}

// ---------------- aggregation: one wave per dst node, 8-deep batched gathers ----------------
__global__ __launch_bounds__(256)
void aggregate(const unsigned short* __restrict__ Yall, const int* __restrict__ mstart,
               const int* __restrict__ mrec, const float* __restrict__ mw,
               const float* __restrict__ bias, unsigned short* __restrict__ hout) {
    int wid = (blockIdx.x * 256 + threadIdx.x) >> 6;
    int lane = threadIdx.x & 63;
    if (wid >= N_NODES) return;
    int d = wid;
    int s = mstart[d], e = mstart[d + 1];

    float2 b2 = *(const float2*)&bias[lane * 2];
    unsigned rv = *(const unsigned*)&Yall[(size_t)d * HID + lane * 2];
    float s0 = b2.x + bf2f((unsigned short)(rv & 0xffff));
    float s1 = b2.y + bf2f((unsigned short)(rv >> 16));

    for (int base = s; base < e; base += 64) {
        int m = min(e - base, 64);
        int rec = 0; float w = 0.f;
        if (lane < m) { rec = mrec[base + lane]; w = mw[base + lane]; }
        for (int j = 0; j < m; j += 8) {
            int g = min(8, m - j);
            unsigned v[8]; float wj[8];
            #pragma unroll
            for (int t = 0; t < 8; t++) {
                if (t < g) {
                    int off = __shfl(rec, j + t, 64);
                    wj[t] = __shfl(w, j + t, 64);
                    v[t] = *(const unsigned*)&Yall[(size_t)off + lane * 2];
                } else { v[t] = 0u; wj[t] = 0.f; }
            }
            #pragma unroll
            for (int t = 0; t < 8; t++) {
                s0 += wj[t] * bf2f((unsigned short)(v[t] & 0xffff));
                s1 += wj[t] * bf2f((unsigned short)(v[t] >> 16));
            }
        }
    }
    unsigned lo = (unsigned short)f2bf(fmaxf(s0, 0.f));
    unsigned hi = (unsigned short)f2bf(fmaxf(s1, 0.f));
    *(unsigned*)&hout[(size_t)d * HID + lane * 2] = lo | (hi << 16);
}

// ---------------- readout ----------------
__global__ __launch_bounds__(128)
void k_pool(const unsigned short* __restrict__ h, const int* __restrict__ batch,
            float* __restrict__ pooled) {
    int c = threadIdx.x;
    int start = blockIdx.x * 128;
    if (start >= N_NODES) return;
    int end = min(start + 128, N_NODES);
    int g = batch[start];
    float s = 0.f;
    for (int i = start; i < end; i++) {
        int gi = batch[i];
        if (gi != g) { atomicAdd(&pooled[g * HID + c], s); s = 0.f; g = gi; }
        s += bf2f(h[(size_t)i * HID + c]);
    }
    atomicAdd(&pooled[g * HID + c], s);
}

__device__ int lower_bound_i(const int* a, int n, int v) {
    int lo = 0, hi = n;
    while (lo < hi) {
        int mid = (lo + hi) >> 1;
        if (a[mid] < v) lo = mid + 1; else hi = mid;
    }
    return lo;
}

__global__ __launch_bounds__(128)
void k_mlp(const float* __restrict__ pooled, const int* __restrict__ batch,
           const float* __restrict__ Wc1, const float* __restrict__ bc1,
           const float* __restrict__ Wc2, const float* __restrict__ bc2,
           const float* __restrict__ Wc3, const float* __restrict__ bc3,
           float* __restrict__ out) {
    int g = blockIdx.x;
    int c = threadIdx.x;
    __shared__ int range[2];
    if (c == 0) range[0] = lower_bound_i(batch, N_NODES, g);
    if (c == 1) range[1] = lower_bound_i(batch, N_NODES, g + 1);
    __syncthreads();
    float denom = fmaxf((float)(range[1] - range[0]), 1.0f);
    __shared__ float row[HID], h1[HID], h2[HID];
    row[c] = pooled[g * HID + c] / denom;
    __syncthreads();
    float acc = bc1[c];
    for (int k = 0; k < HID; k++) acc += row[k] * Wc1[k * HID + c];
    h1[c] = fmaxf(acc, 0.f);
    __syncthreads();
    acc = bc2[c];
    for (int k = 0; k < HID; k++) acc += h1[k] * Wc2[k * HID + c];
    h2[c] = fmaxf(acc, 0.f);
    __syncthreads();
    float t = h2[c] * Wc3[c];
    for (int off = 32; off > 0; off >>= 1) t += __shfl_down(t, off, 64);
    __shared__ float part[2];
    if ((c & 63) == 0) part[c >> 6] = t;
    __syncthreads();
    if (c == 0) out[g] = part[0] + part[1] + bc3[0];
}

// ---------------- launcher ----------------
extern "C" void kernel_launch(void* const* d_in, const int* in_sizes, int n_in,
                              void* d_out, int out_size, void* d_ws, size_t ws_size,
                              hipStream_t stream) {
    const float* X     = (const float*)d_in[0];
    const int*   batch = (const int*)d_in[1];
    const int*   e0 = (const int*)d_in[2];
    const int*   e1 = (const int*)d_in[3];
    const int*   e2 = (const int*)d_in[4];
    const int*   e3 = (const int*)d_in[5];
    const int*   e4 = (const int*)d_in[6];
    const float* W0    = (const float*)d_in[7];
    const float* root0 = (const float*)d_in[8];
    const float* b0    = (const float*)d_in[9];
    const float* Wl    = (const float*)d_in[10];
    const float* rootl = (const float*)d_in[11];
    const float* bl    = (const float*)d_in[12];
    const float* Wc1   = (const float*)d_in[13];
    const float* bc1   = (const float*)d_in[14];
    const float* Wc2   = (const float*)d_in[15];
    const float* bc2   = (const float*)d_in[16];
    const float* Wc3   = (const float*)d_in[17];
    const float* bc3   = (const float*)d_in[18];
    const int E = in_sizes[2] / 2;
    const int NE = R_REL * E;

    char* base = (char*)d_ws;
    size_t o = 0;
    auto carve = [&](size_t bytes) -> char* {
        char* p = base + o;
        o = (o + bytes + 255) & ~(size_t)255;
        return p;
    };
    unsigned short* Y    = (unsigned short*)carve((size_t)6 * NPAD * HID * 2);
    unsigned short* hA   = (unsigned short*)carve((size_t)NPAD * HID * 2);
    unsigned short* hB   = (unsigned short*)carve((size_t)NPAD * HID * 2);
    int*   cnt    = (int*)carve((size_t)M5 * 4);
    float* invc   = (float*)carve((size_t)M5 * 4);
    int*   offsc  = (int*)carve((size_t)N_NODES * 4);
    int*   mstart = (int*)carve((size_t)(N_NODES + 1) * 4);
    int*   mcur   = (int*)carve((size_t)N_NODES * 4);
    int*   mrec   = (int*)carve((size_t)NE * 4);
    float* mw     = (float*)carve((size_t)NE * 4);
    int*   bsum   = (int*)carve(2048);
    float* pooled = (float*)carve((size_t)G_GRAPHS * HID * 4);
    short* Wt0    = (short*)carve((size_t)6 * 128 * KPAD0 * 2);
    short* Wtl    = (short*)carve((size_t)L_LAYERS * 6 * 128 * HID * 2);

    // ---- CSR build + weight prep ----
    hipMemsetAsync(cnt, 0, (size_t)M5 * 4, stream);
    hipMemsetAsync(pooled, 0, (size_t)G_GRAPHS * HID * 4, stream);
    int eg = (NE + 255) / 256;
    k_count<<<eg, 256, 0, stream>>>(e0, e1, e2, e3, e4, cnt, E);
    int nblk = (N_NODES + 1023) / 1024;   // 98
    k_scan1<<<nblk, 256, 0, stream>>>(cnt, offsc, bsum);
    k_scan2<<<1, 512, 0, stream>>>(bsum, nblk);
    k_scan3<<<(N_NODES + 255) / 256, 256, 0, stream>>>(offsc, bsum, mstart, mcur, cnt, invc);
    k_fill<<<eg, 256, 0, stream>>>(e0, e1, e2, e3, e4, mcur, invc, mrec, mw, E);
    k_tw0<<<(6 * 128 * KPAD0 + 255) / 256, 256, 0, stream>>>(root0, W0, Wt0);
    k_twl<<<(L_LAYERS * 6 * 128 * HID + 255) / 256, 256, 0, stream>>>(rootl, Wl, Wtl);

    int agg_grid = (N_NODES + 3) / 4;     // one wave per node, 4 waves/block

    // ---- layer 0: A = X fp32 direct (K=192 padded) ----
    gemm_reg<KPAD0, true, 2><<<NTILES, 256, 0, stream>>>(X, Wt0, Y);
    aggregate<<<agg_grid, 256, 0, stream>>>(Y, mstart, mrec, mw, b0, hA);

    // ---- layers 1..2 (K=128, bf16 A) ----
    unsigned short* hin = hA; unsigned short* hout = hB;
    for (int l = 0; l < L_LAYERS; l++) {
        gemm_reg<HID, false, 3><<<NTILES, 256, 0, stream>>>(hin, Wtl + (size_t)l * 6 * 128 * HID, Y);
        aggregate<<<agg_grid, 256, 0, stream>>>(Y, mstart, mrec, mw, bl + (size_t)l * HID, hout);
        unsigned short* t = hin; hin = hout; hout = t;
    }

    // ---- readout ----
    k_pool<<<(N_NODES + 127) / 128, 128, 0, stream>>>(hin, batch, pooled);
    k_mlp<<<G_GRAPHS, 128, 0, stream>>>(pooled, batch, Wc1, bc1, Wc2, bc2, Wc3, bc3, (float*)d_out);
}

// Round 8
// 727.392 us; speedup vs baseline: 2.8819x; 1.0155x over previous
//
#include <hip/hip_runtime.h>

#define N_NODES 100000
#define NPAD    100096      // 782 * 128
#define NTILES  782
#define G_GRAPHS 256
#define IN_F 162
#define KPAD0 192
#define HID 128
#define R_REL 5
#define L_LAYERS 2
#define M5 (R_REL * N_NODES)

typedef __attribute__((ext_vector_type(8))) short bf16x8;
typedef __attribute__((ext_vector_type(4))) float f32x4;

__device__ __forceinline__ short f2bf(float f) {
    union { float f; unsigned u; } v; v.f = f;
    unsigned r = (v.u + 0x7fffu + ((v.u >> 16) & 1u)) >> 16;
    return (short)r;
}
__device__ __forceinline__ float bf2f(unsigned short u) {
    union { unsigned u; float f; } v; v.u = ((unsigned)u) << 16;
    return v.f;
}

// ---------------- CSR build (merged across relations, dst-major) ----------------
__global__ void k_count(const int* e0, const int* e1, const int* e2,
                        const int* e3, const int* e4, int* cnt, int E) {
    int gid = blockIdx.x * 256 + threadIdx.x;
    if (gid >= R_REL * E) return;
    int r = gid / E, e = gid - r * E;
    const int* ei = (r == 0) ? e0 : (r == 1) ? e1 : (r == 2) ? e2 : (r == 3) ? e3 : e4;
    atomicAdd(&cnt[r * N_NODES + ei[E + e]], 1);
}

__global__ __launch_bounds__(256) void k_scan1(const int* __restrict__ cnt,
                                               int* __restrict__ off, int* __restrict__ bsum) {
    __shared__ int ts[256];
    int t = threadIdx.x;
    int base = blockIdx.x * 1024 + t * 4;
    int v[4];
    #pragma unroll
    for (int j = 0; j < 4; j++) {
        int d = base + j;
        int s = 0;
        if (d < N_NODES) {
            #pragma unroll
            for (int r = 0; r < R_REL; r++) s += cnt[r * N_NODES + d];
        }
        v[j] = s;
    }
    int tsum = v[0] + v[1] + v[2] + v[3];
    ts[t] = tsum; __syncthreads();
    for (int o = 1; o < 256; o <<= 1) {
        int x = (t >= o) ? ts[t - o] : 0;
        __syncthreads();
        ts[t] += x;
        __syncthreads();
    }
    if (t == 255) bsum[blockIdx.x] = ts[255];
    int run = ts[t] - tsum;
    #pragma unroll
    for (int j = 0; j < 4; j++) { if (base + j < N_NODES) off[base + j] = run; run += v[j]; }
}

__global__ __launch_bounds__(512) void k_scan2(int* bsum, int nblk) {
    __shared__ int ts[512];
    int t = threadIdx.x;
    int v = (t < nblk) ? bsum[t] : 0;
    ts[t] = v; __syncthreads();
    for (int o = 1; o < 512; o <<= 1) {
        int x = (t >= o) ? ts[t - o] : 0;
        __syncthreads();
        ts[t] += x;
        __syncthreads();
    }
    if (t < nblk) bsum[t] = ts[t] - v;   // exclusive
}

__global__ void k_scan3(const int* __restrict__ off, const int* __restrict__ bsum,
                        int* __restrict__ mstart, int* __restrict__ mcur,
                        const int* __restrict__ cnt, float* __restrict__ invc) {
    int i = blockIdx.x * 256 + threadIdx.x;
    if (i >= N_NODES) return;
    int o = off[i] + bsum[i >> 10];
    mstart[i] = o;
    mcur[i] = o;
    int tc = 0;
    #pragma unroll
    for (int r = 0; r < R_REL; r++) {
        int c = cnt[r * N_NODES + i];
        tc += c;
        invc[r * N_NODES + i] = 1.0f / (float)max(c, 1);
    }
    if (i == N_NODES - 1) mstart[N_NODES] = o + tc;
}

// mrec = absolute ushort-offset of source row in Y; mw = 1/deg(dst, r)
__global__ void k_fill(const int* e0, const int* e1, const int* e2,
                       const int* e3, const int* e4, int* mcur,
                       const float* __restrict__ invc,
                       int* __restrict__ mrec, float* __restrict__ mw, int E) {
    int gid = blockIdx.x * 256 + threadIdx.x;
    if (gid >= R_REL * E) return;
    int r = gid / E, e = gid - r * E;
    const int* ei = (r == 0) ? e0 : (r == 1) ? e1 : (r == 2) ? e2 : (r == 3) ? e3 : e4;
    int src = ei[e], dst = ei[E + e];
    int pos = atomicAdd(&mcur[dst], 1);
    mrec[pos] = ((1 + r) * NPAD + src) * HID;
    mw[pos] = invc[r * N_NODES + dst];
}

// ---------------- weight pre-transpose (fp32 -> bf16, [chunk][col][Kpad]) ----------------
__global__ void k_tw0(const float* __restrict__ root0, const float* __restrict__ W0,
                      short* __restrict__ out) {
    int gid = blockIdx.x * 256 + threadIdx.x;   // 6*128*192
    if (gid >= 6 * 128 * KPAD0) return;
    int chunk = gid / (128 * KPAD0);
    int rem = gid - chunk * 128 * KPAD0;
    int col = rem / KPAD0;
    int k = rem - col * KPAD0;
    float v = 0.f;
    if (k < IN_F)
        v = (chunk == 0) ? root0[k * HID + col]
                         : W0[((size_t)(chunk - 1) * IN_F + k) * HID + col];
    out[gid] = f2bf(v);
}

__global__ void k_twl(const float* __restrict__ rootl, const float* __restrict__ Wl,
                      short* __restrict__ out) {
    int gid = blockIdx.x * 256 + threadIdx.x;   // 2*6*128*128
    if (gid >= L_LAYERS * 6 * 128 * HID) return;
    int l = gid / (6 * 128 * HID);
    int rem = gid - l * 6 * 128 * HID;
    int chunk = rem / (128 * HID);
    int rem2 = rem - chunk * 128 * HID;
    int col = rem2 / HID;
    int k = rem2 - col * HID;
    float v = (chunk == 0) ? rootl[((size_t)l * HID + k) * HID + col]
                           : Wl[(((size_t)l * R_REL + (chunk - 1)) * HID + k) * HID + col];
    out[gid] = f2bf(v);
}

// ---------------- A-fragment loader (bf16 direct or fp32->bf16 on the fly) ----------------
template<int SEG, bool A_F32>
__device__ __forceinline__ bf16x8 load_af(const void* __restrict__ Av, int grow,
                                          int kb, int quad) {
    bf16x8 v = (bf16x8){0, 0, 0, 0, 0, 0, 0, 0};
    if (A_F32) {
        if (grow < N_NODES) {
            const float* rp = (const float*)Av + (size_t)grow * IN_F;
            int k = kb * 32 + quad * 8;
            if (k + 8 <= IN_F) {
                #pragma unroll
                for (int h = 0; h < 4; h++) {
                    float2 f2 = *(const float2*)(rp + k + 2 * h);
                    v[2 * h] = f2bf(f2.x); v[2 * h + 1] = f2bf(f2.y);
                }
            } else {
                #pragma unroll
                for (int j = 0; j < 8; j++) {
                    int kk = k + j;
                    float f = (kk < IN_F) ? rp[kk] : 0.f;
                    v[j] = f2bf(f);
                }
            }
        }
    } else {
        v = *(const bf16x8*)((const unsigned short*)Av + (size_t)grow * SEG + kb * 32 + quad * 8);
    }
    return v;
}

// ---------------- MFMA GEMM: one block = one (tile, chunk); tile-major XCD swizzle ----------------
// The 6 chunk-blocks of a tile run adjacently on ONE XCD -> A tile is L2-hot for chunks 1..5.
template<int SEG, bool A_F32>
__global__ __launch_bounds__(256)
void gemm_direct(const void* __restrict__ Av, const short* __restrict__ Wt,
                 unsigned short* __restrict__ Y) {
    constexpr int KSEG = SEG / 32;                 // 4 (K=128) or 6 (K=192)
    constexpr int PF = (KSEG > 4) ? 2 : KSEG;      // A-prefetch batch
    constexpr int SBP = SEG + 8;                   // LDS row stride (shorts)
    __shared__ short Bs[128 * SBP];

    // tile-major mapping: xcd = bid&7 (HW round-robin), chunks of a tile adjacent in slot order
    int bid = blockIdx.x;
    int xcd = bid & 7, slot = bid >> 3;
    int tl = slot / 6, chunk = slot - tl * 6;
    int rt = tl * 8 + xcd;
    if (rt >= NTILES) return;
    const int row0 = rt * 128;

    const int tid = threadIdx.x;
    const int lane = tid & 63, wv = tid >> 6;
    const int quad = lane >> 4, l16 = lane & 15;
    const int wr0 = (wv >> 1) * 64, wc0 = (wv & 1) * 64;

    // prefetch first A batch (global, independent of LDS staging)
    bf16x8 cur[PF][4], nxt[PF][4];
    #pragma unroll
    for (int p = 0; p < PF; p++)
        #pragma unroll
        for (int i = 0; i < 4; i++)
            cur[p][i] = load_af<SEG, A_F32>(Av, row0 + wr0 + i * 16 + l16, p, quad);

    // stage B (this chunk's weights; L2-hot: shared by all tiles)
    const short* Wc = Wt + (size_t)chunk * 128 * SEG;
    for (int c = tid; c < 128 * (SEG / 8); c += 256) {
        int r = c / (SEG / 8), c8 = (c - r * (SEG / 8)) * 8;
        *(bf16x8*)&Bs[r * SBP + c8] = *(const bf16x8*)&Wc[r * SEG + c8];
    }
    __syncthreads();

    f32x4 acc[4][4];
    #pragma unroll
    for (int i = 0; i < 4; i++)
        #pragma unroll
        for (int j = 0; j < 4; j++) acc[i][j] = (f32x4){0.f, 0.f, 0.f, 0.f};

    for (int kb = 0; kb < KSEG; kb += PF) {
        if (kb + PF < KSEG) {
            #pragma unroll
            for (int p = 0; p < PF; p++)
                #pragma unroll
                for (int i = 0; i < 4; i++)
                    nxt[p][i] = load_af<SEG, A_F32>(Av, row0 + wr0 + i * 16 + l16,
                                                    kb + PF + p, quad);
        }
        #pragma unroll
        for (int p = 0; p < PF; p++) {
            int k0 = (kb + p) * 32;
            bf16x8 bfr[4];
            #pragma unroll
            for (int j = 0; j < 4; j++)
                bfr[j] = *(const bf16x8*)&Bs[(wc0 + j * 16 + l16) * SBP + k0 + quad * 8];
            #pragma unroll
            for (int i = 0; i < 4; i++)
                #pragma unroll
                for (int j = 0; j < 4; j++)
                    acc[i][j] = __builtin_amdgcn_mfma_f32_16x16x32_bf16(cur[p][i], bfr[j], acc[i][j], 0, 0, 0);
        }
        #pragma unroll
        for (int p = 0; p < PF; p++)
            #pragma unroll
            for (int i = 0; i < 4; i++)
                cur[p][i] = nxt[p][i];
    }
    __syncthreads();   // all waves done reading Bs

    // epilogue: acc -> Bs (bf16), then full-line coalesced stores
    #pragma unroll
    for (int i = 0; i < 4; i++)
        #pragma unroll
        for (int j = 0; j < 4; j++)
            #pragma unroll
            for (int reg = 0; reg < 4; reg++)
                Bs[(wr0 + i * 16 + quad * 4 + reg) * SBP + wc0 + j * 16 + l16] =
                    f2bf(acc[i][j][reg]);
    __syncthreads();

    unsigned short* Yc = Y + (size_t)chunk * NPAD * HID + (size_t)row0 * HID;
    #pragma unroll
    for (int s = 0; s < 8; s++) {
        int row = (tid >> 4) + s * 16;
        int col = (tid & 15) * 8;
        bf16x8 v = *(const bf16x8*)&Bs[row * SBP + col];
        *(bf16x8*)&Yc[(size_t)row * HID + col] = v;
    }
}

// ---------------- aggregation: one wave per dst node, 8-deep batched gathers ----------------
__global__ __launch_bounds__(256)
void aggregate(const unsigned short* __restrict__ Yall, const int* __restrict__ mstart,
               const int* __restrict__ mrec, const float* __restrict__ mw,
               const float* __restrict__ bias, unsigned short* __restrict__ hout) {
    int wid = (blockIdx.x * 256 + threadIdx.x) >> 6;
    int lane = threadIdx.x & 63;
    if (wid >= N_NODES) return;
    int d = wid;
    int s = mstart[d], e = mstart[d + 1];

    float2 b2 = *(const float2*)&bias[lane * 2];
    unsigned rv = *(const unsigned*)&Yall[(size_t)d * HID + lane * 2];
    float s0 = b2.x + bf2f((unsigned short)(rv & 0xffff));
    float s1 = b2.y + bf2f((unsigned short)(rv >> 16));

    for (int base = s; base < e; base += 64) {
        int m = min(e - base, 64);
        int rec = 0; float w = 0.f;
        if (lane < m) { rec = mrec[base + lane]; w = mw[base + lane]; }
        for (int j = 0; j < m; j += 8) {
            int g = min(8, m - j);
            unsigned v[8]; float wj[8];
            #pragma unroll
            for (int t = 0; t < 8; t++) {
                if (t < g) {
                    int off = __shfl(rec, j + t, 64);
                    wj[t] = __shfl(w, j + t, 64);
                    v[t] = *(const unsigned*)&Yall[(size_t)off + lane * 2];
                } else { v[t] = 0u; wj[t] = 0.f; }
            }
            #pragma unroll
            for (int t = 0; t < 8; t++) {
                s0 += wj[t] * bf2f((unsigned short)(v[t] & 0xffff));
                s1 += wj[t] * bf2f((unsigned short)(v[t] >> 16));
            }
        }
    }
    unsigned lo = (unsigned short)f2bf(fmaxf(s0, 0.f));
    unsigned hi = (unsigned short)f2bf(fmaxf(s1, 0.f));
    *(unsigned*)&hout[(size_t)d * HID + lane * 2] = lo | (hi << 16);
}

// ---------------- readout ----------------
__global__ __launch_bounds__(128)
void k_pool(const unsigned short* __restrict__ h, const int* __restrict__ batch,
            float* __restrict__ pooled) {
    int c = threadIdx.x;
    int start = blockIdx.x * 128;
    if (start >= N_NODES) return;
    int end = min(start + 128, N_NODES);
    int g = batch[start];
    float s = 0.f;
    for (int i = start; i < end; i++) {
        int gi = batch[i];
        if (gi != g) { atomicAdd(&pooled[g * HID + c], s); s = 0.f; g = gi; }
        s += bf2f(h[(size_t)i * HID + c]);
    }
    atomicAdd(&pooled[g * HID + c], s);
}

__device__ int lower_bound_i(const int* a, int n, int v) {
    int lo = 0, hi = n;
    while (lo < hi) {
        int mid = (lo + hi) >> 1;
        if (a[mid] < v) lo = mid + 1; else hi = mid;
    }
    return lo;
}

__global__ __launch_bounds__(128)
void k_mlp(const float* __restrict__ pooled, const int* __restrict__ batch,
           const float* __restrict__ Wc1, const float* __restrict__ bc1,
           const float* __restrict__ Wc2, const float* __restrict__ bc2,
           const float* __restrict__ Wc3, const float* __restrict__ bc3,
           float* __restrict__ out) {
    int g = blockIdx.x;
    int c = threadIdx.x;
    __shared__ int range[2];
    if (c == 0) range[0] = lower_bound_i(batch, N_NODES, g);
    if (c == 1) range[1] = lower_bound_i(batch, N_NODES, g + 1);
    __syncthreads();
    float denom = fmaxf((float)(range[1] - range[0]), 1.0f);
    __shared__ float row[HID], h1[HID], h2[HID];
    row[c] = pooled[g * HID + c] / denom;
    __syncthreads();
    float acc = bc1[c];
    for (int k = 0; k < HID; k++) acc += row[k] * Wc1[k * HID + c];
    h1[c] = fmaxf(acc, 0.f);
    __syncthreads();
    acc = bc2[c];
    for (int k = 0; k < HID; k++) acc += h1[k] * Wc2[k * HID + c];
    h2[c] = fmaxf(acc, 0.f);
    __syncthreads();
    float t = h2[c] * Wc3[c];
    for (int off = 32; off > 0; off >>= 1) t += __shfl_down(t, off, 64);
    __shared__ float part[2];
    if ((c & 63) == 0) part[c >> 6] = t;
    __syncthreads();
    if (c == 0) out[g] = part[0] + part[1] + bc3[0];
}

// ---------------- launcher ----------------
extern "C" void kernel_launch(void* const* d_in, const int* in_sizes, int n_in,
                              void* d_out, int out_size, void* d_ws, size_t ws_size,
                              hipStream_t stream) {
    const float* X     = (const float*)d_in[0];
    const int*   batch = (const int*)d_in[1];
    const int*   e0 = (const int*)d_in[2];
    const int*   e1 = (const int*)d_in[3];
    const int*   e2 = (const int*)d_in[4];
    const int*   e3 = (const int*)d_in[5];
    const int*   e4 = (const int*)d_in[6];
    const float* W0    = (const float*)d_in[7];
    const float* root0 = (const float*)d_in[8];
    const float* b0    = (const float*)d_in[9];
    const float* Wl    = (const float*)d_in[10];
    const float* rootl = (const float*)d_in[11];
    const float* bl    = (const float*)d_in[12];
    const float* Wc1   = (const float*)d_in[13];
    const float* bc1   = (const float*)d_in[14];
    const float* Wc2   = (const float*)d_in[15];
    const float* bc2   = (const float*)d_in[16];
    const float* Wc3   = (const float*)d_in[17];
    const float* bc3   = (const float*)d_in[18];
    const int E = in_sizes[2] / 2;
    const int NE = R_REL * E;

    char* base = (char*)d_ws;
    size_t o = 0;
    auto carve = [&](size_t bytes) -> char* {
        char* p = base + o;
        o = (o + bytes + 255) & ~(size_t)255;
        return p;
    };
    unsigned short* Y    = (unsigned short*)carve((size_t)6 * NPAD * HID * 2);
    unsigned short* hA   = (unsigned short*)carve((size_t)NPAD * HID * 2);
    unsigned short* hB   = (unsigned short*)carve((size_t)NPAD * HID * 2);
    int*   cnt    = (int*)carve((size_t)M5 * 4);
    float* invc   = (float*)carve((size_t)M5 * 4);
    int*   offsc  = (int*)carve((size_t)N_NODES * 4);
    int*   mstart = (int*)carve((size_t)(N_NODES + 1) * 4);
    int*   mcur   = (int*)carve((size_t)N_NODES * 4);
    int*   mrec   = (int*)carve((size_t)NE * 4);
    float* mw     = (float*)carve((size_t)NE * 4);
    int*   bsum   = (int*)carve(2048);
    float* pooled = (float*)carve((size_t)G_GRAPHS * HID * 4);
    short* Wt0    = (short*)carve((size_t)6 * 128 * KPAD0 * 2);
    short* Wtl    = (short*)carve((size_t)L_LAYERS * 6 * 128 * HID * 2);

    // ---- CSR build + weight prep ----
    hipMemsetAsync(cnt, 0, (size_t)M5 * 4, stream);
    hipMemsetAsync(pooled, 0, (size_t)G_GRAPHS * HID * 4, stream);
    int eg = (NE + 255) / 256;
    k_count<<<eg, 256, 0, stream>>>(e0, e1, e2, e3, e4, cnt, E);
    int nblk = (N_NODES + 1023) / 1024;   // 98
    k_scan1<<<nblk, 256, 0, stream>>>(cnt, offsc, bsum);
    k_scan2<<<1, 512, 0, stream>>>(bsum, nblk);
    k_scan3<<<(N_NODES + 255) / 256, 256, 0, stream>>>(offsc, bsum, mstart, mcur, cnt, invc);
    k_fill<<<eg, 256, 0, stream>>>(e0, e1, e2, e3, e4, mcur, invc, mrec, mw, E);
    k_tw0<<<(6 * 128 * KPAD0 + 255) / 256, 256, 0, stream>>>(root0, W0, Wt0);
    k_twl<<<(L_LAYERS * 6 * 128 * HID + 255) / 256, 256, 0, stream>>>(rootl, Wl, Wtl);

    int ggrid = 8 * 98 * 6;               // 4704 blocks, tile-major per XCD
    int agg_grid = (N_NODES + 3) / 4;     // one wave per node, 4 waves/block

    // ---- layer 0: A = X fp32 direct (K=192 padded) ----
    gemm_direct<KPAD0, true><<<ggrid, 256, 0, stream>>>(X, Wt0, Y);
    aggregate<<<agg_grid, 256, 0, stream>>>(Y, mstart, mrec, mw, b0, hA);

    // ---- layers 1..2 (K=128, bf16 A) ----
    unsigned short* hin = hA; unsigned short* hout = hB;
    for (int l = 0; l < L_LAYERS; l++) {
        gemm_direct<HID, false><<<ggrid, 256, 0, stream>>>(hin, Wtl + (size_t)l * 6 * 128 * HID, Y);
        aggregate<<<agg_grid, 256, 0, stream>>>(Y, mstart, mrec, mw, bl + (size_t)l * HID, hout);
        unsigned short* t = hin; hin = hout; hout = t;
    }

    // ---- readout ----
    k_pool<<<(N_NODES + 127) / 128, 128, 0, stream>>>(hin, batch, pooled);
    k_mlp<<<G_GRAPHS, 128, 0, stream>>>(pooled, batch, Wc1, bc1, Wc2, bc2, Wc3, bc3, (float*)d_out);
}